// Round 6
// baseline (34.898 us; speedup 1.0000x reference)
//
#include <hip/hip_runtime.h>

// JaggedAppend: out = concat_i( values[seg_i] ++ suffix_mat[i] )
// R6: flat balanced decomposition. Each block owns a fixed CHUNK-float span
// of the OUTPUT (equal bytes/block), binary-searches its starting segment in
// new_prefix (= prefix_sum[i] + (i+1)*SUF, computed on the fly), then walks
// segments intersecting its span. Value copies use dst-aligned float4 (src
// shares phase: new_start - prev_old = seg*1024B); suffix parts scalar.

#define SUF 256
#define NTHR 256
#define CHUNK 8192  // output floats per block (32 KB)

typedef float floatx4 __attribute__((ext_vector_type(4)));

__device__ __forceinline__ void copy_same_phase(float* __restrict__ dst,
                                                const float* __restrict__ src,
                                                int n, int tid) {
    // Requires: src and dst have identical alignment phase mod 16B.
    int head = (4 - (((unsigned)(size_t)dst >> 2) & 3)) & 3;
    if (head > n) head = n;
    if (tid < head) dst[tid] = src[tid];
    const int nvec = (n - head) >> 2;
    const floatx4* __restrict__ vs = (const floatx4*)(src + head);
    floatx4* __restrict__ vd = (floatx4*)(dst + head);
    for (int v = tid; v < nvec; v += NTHR) vd[v] = vs[v];
    for (int i = head + (nvec << 2) + tid; i < n; i += NTHR) dst[i] = src[i];
}

__global__ __launch_bounds__(NTHR) void
jagged_append_flat(const float* __restrict__ values,
                   const int* __restrict__ prefix_sum,
                   const float* __restrict__ suffix,
                   float* __restrict__ out,
                   int B, int n_out) {
    const int tid = threadIdx.x;
    const int span_s = blockIdx.x * CHUNK;
    if (span_s >= n_out) return;
    const int span_e = min(span_s + CHUNK, n_out);

    // Smallest seg with new_prefix[seg] > span_s (wave-uniform, scalar-cached).
    int lo = 0, hi = B - 1;
    while (lo < hi) {
        int mid = (lo + hi) >> 1;
        int np = prefix_sum[mid] + (mid + 1) * SUF;
        if (np > span_s) hi = mid; else lo = mid + 1;
    }
    int seg = lo;
    int ps_prev = (seg > 0) ? prefix_sum[seg - 1] : 0;

    int s = span_s;
    while (s < span_e && seg < B) {
        const int ps_cur = prefix_sum[seg];
        const int new_start = ps_prev + seg * SUF;   // out index where segment starts
        const int seg_len = ps_cur - ps_prev;
        const int vals_end = new_start + seg_len;    // out index where suffix starts
        const int seg_end = vals_end + SUF;

        // Value part ∩ span.
        int a = s > new_start ? s : new_start;
        int b = span_e < vals_end ? span_e : vals_end;
        if (a < b) copy_same_phase(out + a, values + (a - seg * SUF), b - a, tid);

        // Suffix part ∩ span (scalar; src/dst phases differ).
        int c = s > vals_end ? s : vals_end;
        int d = span_e < seg_end ? span_e : seg_end;
        if (c < d) {
            const float* __restrict__ sf = suffix + seg * SUF + (c - vals_end);
            float* __restrict__ od = out + c;
            const int n = d - c;
            for (int i = tid; i < n; i += NTHR) od[i] = sf[i];
        }

        s = seg_end;
        ++seg;
        ps_prev = ps_cur;
    }
}

extern "C" void kernel_launch(void* const* d_in, const int* in_sizes, int n_in,
                              void* d_out, int out_size, void* d_ws, size_t ws_size,
                              hipStream_t stream) {
    const float* values     = (const float*)d_in[0];
    const int*   prefix_sum = (const int*)d_in[1];
    const float* suffix     = (const float*)d_in[2];
    float* out = (float*)d_out;

    const int B = in_sizes[1];  // 8192 segments
    const int nblocks = (out_size + CHUNK - 1) / CHUNK;

    jagged_append_flat<<<nblocks, NTHR, 0, stream>>>(values, prefix_sum, suffix,
                                                     out, B, out_size);
}